// Round 4
// baseline (2632.759 us; speedup 1.0000x reference)
//
#include <hip/hip_runtime.h>
#include <hip/hip_bf16.h>

#define BB 4
#define NN 4096
#define KK 16
#define DP 64
#define DM 128
#define DMP 132   // padded LDS row stride (floats); 528 B, 16B-aligned
#define EPSF 1e-8f
#define OUT0N ((size_t)BB * NN * DP)   // elements in out0

typedef unsigned short u16t;

__device__ int g_flag;   // 0 = buffers are fp32, 1 = buffers are bf16

__device__ __forceinline__ float u2f(u16t u) {
    unsigned int x = ((unsigned int)u) << 16;
    return __uint_as_float(x);
}
__device__ __forceinline__ u16t f2u(float v) {
    __hip_bfloat16 h = __float2bfloat16(v);
    return *(u16t*)&h;
}

// ---------------- dtype-abstracted IO -----------------
template<int DT> struct IO;
template<> struct IO<0> {   // fp32
    static __device__ __forceinline__ float ld(const void* p, size_t i) { return ((const float*)p)[i]; }
    static __device__ __forceinline__ void ld4(const void* p, size_t i, float o[4]) {
        float4 v = *(const float4*)((const float*)p + i);
        o[0] = v.x; o[1] = v.y; o[2] = v.z; o[3] = v.w;
    }
    static __device__ __forceinline__ void st(void* p, size_t i, float v) { ((float*)p)[i] = v; }
};
template<> struct IO<1> {   // bf16
    static __device__ __forceinline__ float ld(const void* p, size_t i) { return u2f(((const u16t*)p)[i]); }
    static __device__ __forceinline__ void ld4(const void* p, size_t i, float o[4]) {
        ushort4 v = *(const ushort4*)((const u16t*)p + i);
        o[0] = u2f(v.x); o[1] = u2f(v.y); o[2] = u2f(v.z); o[3] = u2f(v.w);
    }
    static __device__ __forceinline__ void st(void* p, size_t i, float v) { ((u16t*)p)[i] = f2u(v); }
};

// ---------------- dtype detector ----------------------
// Decode even-indexed 16-bit halves of `features` as bf16. Real bf16 randn
// values are ~always "sane"; fp32 low-mantissa halves decode to random
// exponents (sane ~7% of the time). 64 samples, threshold 32.
__global__ __launch_bounds__(64) void detect_kernel(const void* feat) {
    const int tid = threadIdx.x;
    float x = u2f(((const u16t*)feat)[2 * tid]);
    float a = fabsf(x);
    bool sane = (x == 0.0f) || (a > 1e-4f && a < 50.0f);   // NaN/inf -> false
    unsigned long long m = __ballot(sane);
    if (tid == 0) g_flag = (__popcll(m) >= 32) ? 1 : 0;
}

// ---------------- kernel A: qkv ----------------------
struct QkvSmem { float sf[DP]; float sx[DM]; };

template<int DT>
__device__ __forceinline__ void qkv_body(QkvSmem& s,
    const void* feat, const void* fc1_w, const void* fc1_b,
    const void* wq, const void* wk, const void* wv,
    float* __restrict__ qbuf, float* __restrict__ kbuf, float* __restrict__ vbuf)
{
    const int bn = blockIdx.x;
    const int tid = threadIdx.x;
    if (tid < DP) s.sf[tid] = IO<DT>::ld(feat, (size_t)bn * DP + tid);
    __syncthreads();
    float x = IO<DT>::ld(fc1_b, tid);
#pragma unroll 4
    for (int i = 0; i < DP; i++) x = fmaf(s.sf[i], IO<DT>::ld(fc1_w, i * DM + tid), x);
    s.sx[tid] = x;
    __syncthreads();
    float q = 0.f, k = 0.f, v = 0.f;
    for (int i0 = 0; i0 < DM; i0 += 4) {
        float4 xv = *(const float4*)&s.sx[i0];
        const float xs[4] = { xv.x, xv.y, xv.z, xv.w };
#pragma unroll
        for (int j = 0; j < 4; j++) {
            q = fmaf(xs[j], IO<DT>::ld(wq, (i0 + j) * DM + tid), q);
            k = fmaf(xs[j], IO<DT>::ld(wk, (i0 + j) * DM + tid), k);
            v = fmaf(xs[j], IO<DT>::ld(wv, (i0 + j) * DM + tid), v);
        }
    }
    qbuf[(size_t)bn * DM + tid] = q;
    kbuf[(size_t)bn * DM + tid] = k;
    vbuf[(size_t)bn * DM + tid] = v;
}

__global__ __launch_bounds__(128) void qkv_kernel(
    const void* feat, const void* fc1_w, const void* fc1_b,
    const void* wq, const void* wk, const void* wv,
    float* qbuf, float* kbuf, float* vbuf)
{
    __shared__ __align__(16) QkvSmem s;
    if (g_flag) qkv_body<1>(s, feat, fc1_w, fc1_b, wq, wk, wv, qbuf, kbuf, vbuf);
    else        qkv_body<0>(s, feat, fc1_w, fc1_b, wq, wk, wv, qbuf, kbuf, vbuf);
}

// ---------------- kernel B: knn ----------------------
// Exact fp32 mirror of: sq_i + sq_j - 2*dot, stable top-K (ties -> low index).
struct KnnSmem { float sx[NN]; float sy[NN]; float sz[NN]; };

template<int DT>
__device__ __forceinline__ void knn_body(KnnSmem& s,
    const void* xyz, int* dst, int dstride, void* dout, int in_out)
{
    if (in_out) {
        if (DT) { dst = (int*)((u16t*)dout + OUT0N); dstride = (KK * DM) / 2; }
        else    { dst = (int*)((float*)dout + OUT0N); dstride = KK * DM; }
    }
    const int b = blockIdx.x >> 4;
    const int r0 = (blockIdx.x & 15) * 256;
    const int tid = threadIdx.x;
    for (int j = tid; j < NN; j += 256) {
        s.sx[j] = IO<DT>::ld(xyz, ((size_t)b * NN + j) * 3 + 0);
        s.sy[j] = IO<DT>::ld(xyz, ((size_t)b * NN + j) * 3 + 1);
        s.sz[j] = IO<DT>::ld(xyz, ((size_t)b * NN + j) * 3 + 2);
    }
    __syncthreads();
    const int r = r0 + tid;
    const float xr = s.sx[r], yr = s.sy[r], zr = s.sz[r];
    const float sqr = __fadd_rn(__fadd_rn(__fmul_rn(xr, xr), __fmul_rn(yr, yr)), __fmul_rn(zr, zr));
    float d[KK];
    int id[KK];
#pragma unroll
    for (int t = 0; t < KK; t++) { d[t] = 3.4e38f; id[t] = 0; }
    float dlast = 3.4e38f;
    for (int j = 0; j < NN; j++) {
        const float xj = s.sx[j], yj = s.sy[j], zj = s.sz[j];
        const float sqj = __fadd_rn(__fadd_rn(__fmul_rn(xj, xj), __fmul_rn(yj, yj)), __fmul_rn(zj, zj));
        const float dot = __fadd_rn(__fadd_rn(__fmul_rn(xr, xj), __fmul_rn(yr, yj)), __fmul_rn(zr, zj));
        const float dist = __fsub_rn(__fadd_rn(sqr, sqj), __fmul_rn(2.0f, dot));
        if (dist < dlast) {
            int p = KK - 2;
            while (p >= 0 && d[p] > dist) { d[p + 1] = d[p]; id[p + 1] = id[p]; p--; }
            d[p + 1] = dist; id[p + 1] = j;
            dlast = d[KK - 1];
        }
    }
#pragma unroll
    for (int t = 0; t < KK; t++) dst[(size_t)(b * NN + r) * dstride + t] = id[t];
}

__global__ __launch_bounds__(256) void knn_kernel(
    const void* xyz, int* dst, int dstride, void* dout, int in_out)
{
    __shared__ __align__(16) KnnSmem s;
    if (g_flag) knn_body<1>(s, xyz, dst, dstride, dout, in_out);
    else        knn_body<0>(s, xyz, dst, dstride, dout, in_out);
}

// ---------------- GEMM tile helper -------------------
// OUT[k][f] = sum_i IN[k][i] * W[woff + i*DM + f]; thread owns 4 k x 4 f.
template<int DT>
__device__ __forceinline__ void gemm_tile(const float* __restrict__ IN,
                                          const void* __restrict__ W, int woff,
                                          int kg, int f0, float acc[4][4])
{
#pragma unroll
    for (int a = 0; a < 4; a++)
#pragma unroll
        for (int c = 0; c < 4; c++) acc[a][c] = 0.f;
    for (int i0 = 0; i0 < DM; i0 += 4) {
        float w[4][4];
#pragma unroll
        for (int j = 0; j < 4; j++) IO<DT>::ld4(W, (size_t)woff + (i0 + j) * DM + f0, w[j]);
#pragma unroll
        for (int kk = 0; kk < 4; kk++) {
            float4 x4 = *(const float4*)(IN + (kg * 4 + kk) * DMP + i0);
            const float xs[4] = { x4.x, x4.y, x4.z, x4.w };
#pragma unroll
            for (int ff = 0; ff < 4; ff++)
#pragma unroll
                for (int j = 0; j < 4; j++)
                    acc[kk][ff] = fmaf(xs[j], w[j][ff], acc[kk][ff]);
        }
    }
}

// ---------------- kernel C: attn ---------------------
template<bool FUSED> struct AttnSmem {
    float Kb[KK * DMP], Vb[KK * DMP], PE[KK * DMP], T0[KK * DMP], T1[KK * DMP];
    float s_q[DM], sres[DM];
    float SF[FUSED ? 17 * DP : 1];
    float X[FUSED ? 17 * DMP : 1];
    float srp[KK][3];
    float ssim[KK], skn[KK], sdot[KK];
    float sqn;
    int sidx[KK];
};

template<int DT, bool FUSED>
__device__ __forceinline__ void attn_body(AttnSmem<FUSED>& s,
    const void* xyz, const void* feat,
    const void* fc1_w, const void* fc1_b, const void* fc2_w, const void* fc2_b,
    const void* d1_w, const void* d1_b, const void* d2_w, const void* d2_b,
    const void* g1_w, const void* g1_b, const void* g2_w, const void* g2_b,
    const void* sim_w, const void* sim_b,
    const void* wq, const void* wk, const void* wv,
    const float* __restrict__ qbuf, const float* __restrict__ kbuf, const float* __restrict__ vbuf,
    const int* knn, int knn_stride, int knn_in_out, void* dout)
{
    void* out0 = dout;
    void* out1 = DT ? (void*)((u16t*)dout + OUT0N) : (void*)((float*)dout + OUT0N);
    if (knn_in_out) {
        if (DT) { knn = (const int*)((const u16t*)dout + OUT0N); knn_stride = (KK * DM) / 2; }
        else    { knn = (const int*)((const float*)dout + OUT0N); knn_stride = KK * DM; }
    }

    const int bn = blockIdx.x;
    const int b = bn >> 12;
    const int tid = threadIdx.x;
    const int f = tid;
    const int f0 = (tid & 31) * 4;
    const int kg = tid >> 5;

    if (tid < KK) {
        int sv = knn[(size_t)bn * knn_stride + tid];
        sv = (sv < 0) ? 0 : (sv > NN - 1 ? NN - 1 : sv);   // defensive, never OOB
        s.sidx[tid] = sv;
    }
    __syncthreads();

    if constexpr (FUSED) {
        for (int idx = tid; idx < 17 * DP; idx += 128) {
            const int r = idx >> 6, c = idx & 63;
            const int row = (r < KK) ? ((b << 12) + s.sidx[r]) : bn;
            s.SF[idx] = IO<DT>::ld(feat, (size_t)row * DP + c);
        }
        __syncthreads();
        float xacc[17];
        const float fb = IO<DT>::ld(fc1_b, tid);
#pragma unroll
        for (int r = 0; r < 17; r++) xacc[r] = fb;
        for (int i = 0; i < DP; i++) {
            const float w = IO<DT>::ld(fc1_w, i * DM + tid);
#pragma unroll
            for (int r = 0; r < 17; r++) xacc[r] = fmaf(s.SF[r * DP + i], w, xacc[r]);
        }
#pragma unroll
        for (int r = 0; r < 17; r++) s.X[r * DMP + tid] = xacc[r];
        __syncthreads();
        {
            float a2[4][4];
            gemm_tile<DT>(s.X, wk, 0, kg, f0, a2);
#pragma unroll
            for (int kk = 0; kk < 4; kk++)
                *(float4*)&s.Kb[(kg * 4 + kk) * DMP + f0] =
                    make_float4(a2[kk][0], a2[kk][1], a2[kk][2], a2[kk][3]);
            gemm_tile<DT>(s.X, wv, 0, kg, f0, a2);
#pragma unroll
            for (int kk = 0; kk < 4; kk++)
                *(float4*)&s.Vb[(kg * 4 + kk) * DMP + f0] =
                    make_float4(a2[kk][0], a2[kk][1], a2[kk][2], a2[kk][3]);
        }
        {
            float qv = 0.f;
            for (int i0 = 0; i0 < DM; i0 += 4) {
                float4 x4 = *(const float4*)&s.X[16 * DMP + i0];
                const float xs[4] = { x4.x, x4.y, x4.z, x4.w };
#pragma unroll
                for (int j = 0; j < 4; j++)
                    qv = fmaf(xs[j], IO<DT>::ld(wq, (i0 + j) * DM + tid), qv);
            }
            s.s_q[tid] = qv;
        }
    } else {
        s.s_q[f] = qbuf[(size_t)bn * DM + f];
#pragma unroll
        for (int k = 0; k < KK; k++) {
            const int row = (b << 12) + s.sidx[k];
            s.Kb[k * DMP + f] = kbuf[(size_t)row * DM + f];
            s.Vb[k * DMP + f] = vbuf[(size_t)row * DM + f];
        }
    }
    if (tid < KK) {
        const int row = (b << 12) + s.sidx[tid];
#pragma unroll
        for (int c = 0; c < 3; c++)
            s.srp[tid][c] = IO<DT>::ld(xyz, (size_t)bn * 3 + c) - IO<DT>::ld(xyz, (size_t)row * 3 + c);
    }
    __syncthreads();

    // norms + q.k dots
    if (tid < KK) {
        float sk = 0.f, sd = 0.f;
        for (int i = 0; i < DM; i++) {
            float v2 = s.Kb[tid * DMP + i];
            sk = fmaf(v2, v2, sk);
            sd = fmaf(s.s_q[i], v2, sd);
        }
        s.skn[tid] = fmaxf(sqrtf(sk), EPSF);
        s.sdot[tid] = sd;
    } else if (tid == KK) {
        float sqq = 0.f;
        for (int i = 0; i < DM; i++) { float v2 = s.s_q[i]; sqq = fmaf(v2, v2, sqq); }
        s.sqn = fmaxf(sqrtf(sqq), EPSF);
    }
    __syncthreads();
    if (tid < KK) s.ssim[tid] = s.sdot[tid] / (s.sqn * s.skn[tid]);
#pragma unroll
    for (int k = 0; k < KK; k++) s.T0[k * DMP + f] = s.s_q[f] - s.Kb[k * DMP + f];
    __syncthreads();

    float acc[4][4];

    // rel_qk = [sim, q-k] @ sim_w + sim_b  -> T1
    gemm_tile<DT>(s.T0, sim_w, DM, kg, f0, acc);
    {
        float w0f[4], sbf[4];
        IO<DT>::ld4(sim_w, f0, w0f);
        IO<DT>::ld4(sim_b, f0, sbf);
#pragma unroll
        for (int kk = 0; kk < 4; kk++) {
            float sm = s.ssim[kg * 4 + kk];
            float4 o;
            o.x = fmaf(sm, w0f[0], acc[kk][0]) + sbf[0];
            o.y = fmaf(sm, w0f[1], acc[kk][1]) + sbf[1];
            o.z = fmaf(sm, w0f[2], acc[kk][2]) + sbf[2];
            o.w = fmaf(sm, w0f[3], acc[kk][3]) + sbf[3];
            *(float4*)&s.T1[(kg * 4 + kk) * DMP + f0] = o;
        }
    }
    __syncthreads();

    // h = relu(rel_pos @ d1_w + d1_b) -> T0
    {
        float w0 = IO<DT>::ld(d1_w, 0 * DM + f), w1 = IO<DT>::ld(d1_w, 1 * DM + f),
              w2 = IO<DT>::ld(d1_w, 2 * DM + f);
        float hb = IO<DT>::ld(d1_b, f);
#pragma unroll
        for (int k = 0; k < KK; k++) {
            float h = fmaf(s.srp[k][2], w2, fmaf(s.srp[k][1], w1, fmaf(s.srp[k][0], w0, hb)));
            s.T0[k * DMP + f] = fmaxf(h, 0.f);
        }
    }
    __syncthreads();

    // pos_enc = h @ d2_w + d2_b -> PE
    gemm_tile<DT>(s.T0, d2_w, 0, kg, f0, acc);
    {
        float bf[4];
        IO<DT>::ld4(d2_b, f0, bf);
#pragma unroll
        for (int kk = 0; kk < 4; kk++)
            *(float4*)&s.PE[(kg * 4 + kk) * DMP + f0] =
                make_float4(acc[kk][0] + bf[0], acc[kk][1] + bf[1],
                            acc[kk][2] + bf[2], acc[kk][3] + bf[3]);
    }
    __syncthreads();

    // T0 = T1 + PE
#pragma unroll
    for (int kk = 0; kk < 4; kk++) {
        const int row = (kg * 4 + kk) * DMP + f0;
        float4 a4 = *(const float4*)&s.T1[row];
        float4 p4 = *(const float4*)&s.PE[row];
        *(float4*)&s.T0[row] = make_float4(a4.x + p4.x, a4.y + p4.y, a4.z + p4.z, a4.w + p4.w);
    }
    __syncthreads();

    // T1 = relu(T0 @ g1_w + g1_b)
    gemm_tile<DT>(s.T0, g1_w, 0, kg, f0, acc);
    {
        float bf[4];
        IO<DT>::ld4(g1_b, f0, bf);
#pragma unroll
        for (int kk = 0; kk < 4; kk++)
            *(float4*)&s.T1[(kg * 4 + kk) * DMP + f0] =
                make_float4(fmaxf(acc[kk][0] + bf[0], 0.f), fmaxf(acc[kk][1] + bf[1], 0.f),
                            fmaxf(acc[kk][2] + bf[2], 0.f), fmaxf(acc[kk][3] + bf[3], 0.f));
    }
    __syncthreads();

    // T0 = T1 @ g2_w + g2_b
    gemm_tile<DT>(s.T1, g2_w, 0, kg, f0, acc);
    {
        float bf[4];
        IO<DT>::ld4(g2_b, f0, bf);
#pragma unroll
        for (int kk = 0; kk < 4; kk++)
            *(float4*)&s.T0[(kg * 4 + kk) * DMP + f0] =
                make_float4(acc[kk][0] + bf[0], acc[kk][1] + bf[1],
                            acc[kk][2] + bf[2], acc[kk][3] + bf[3]);
    }
    __syncthreads();

    // softmax over K + einsum
    {
        const float sq128 = 11.31370849898476f;
        float tv[KK];
        float m = -3.4e38f;
#pragma unroll
        for (int k = 0; k < KK; k++) { tv[k] = s.T0[k * DMP + f] / sq128; m = fmaxf(m, tv[k]); }
        float ssum = 0.f;
#pragma unroll
        for (int k = 0; k < KK; k++) { tv[k] = expf(tv[k] - m); ssum += tv[k]; }
        float rf = 0.f;
#pragma unroll
        for (int k = 0; k < KK; k++) {
            float a = tv[k] / ssum;
            IO<DT>::st(out1, ((size_t)bn * KK + k) * DM + f, a);
            rf = fmaf(a, s.Vb[k * DMP + f] + s.PE[k * DMP + f], rf);
        }
        s.sres[f] = rf;
    }
    __syncthreads();

    // out0 = res @ fc2_w + fc2_b + features
    if (tid < DP) {
        float o = 0.f;
        for (int i = 0; i < DM; i++) o = fmaf(s.sres[i], IO<DT>::ld(fc2_w, i * DP + tid), o);
        o = o + IO<DT>::ld(fc2_b, tid) + IO<DT>::ld(feat, (size_t)bn * DP + tid);
        IO<DT>::st(out0, (size_t)bn * DP + tid, o);
    }
}

template<bool FUSED>
__global__ __launch_bounds__(128) void attn_kernel(
    const void* xyz, const void* feat,
    const void* fc1_w, const void* fc1_b, const void* fc2_w, const void* fc2_b,
    const void* d1_w, const void* d1_b, const void* d2_w, const void* d2_b,
    const void* g1_w, const void* g1_b, const void* g2_w, const void* g2_b,
    const void* sim_w, const void* sim_b,
    const void* wq, const void* wk, const void* wv,
    const float* qbuf, const float* kbuf, const float* vbuf,
    const int* knn, int knn_stride, int knn_in_out, void* dout)
{
    __shared__ __align__(16) AttnSmem<FUSED> s;
    if (g_flag)
        attn_body<1, FUSED>(s, xyz, feat, fc1_w, fc1_b, fc2_w, fc2_b, d1_w, d1_b, d2_w, d2_b,
                            g1_w, g1_b, g2_w, g2_b, sim_w, sim_b, wq, wk, wv,
                            qbuf, kbuf, vbuf, knn, knn_stride, knn_in_out, dout);
    else
        attn_body<0, FUSED>(s, xyz, feat, fc1_w, fc1_b, fc2_w, fc2_b, d1_w, d1_b, d2_w, d2_b,
                            g1_w, g1_b, g2_w, g2_b, sim_w, sim_b, wq, wk, wv,
                            qbuf, kbuf, vbuf, knn, knn_stride, knn_in_out, dout);
}

// ---------------------------------------------------------------- launch
extern "C" void kernel_launch(void* const* d_in, const int* in_sizes, int n_in,
                              void* d_out, int out_size, void* d_ws, size_t ws_size,
                              hipStream_t stream)
{
    const void* xyz   = d_in[0];
    const void* feat  = d_in[1];
    const void* fc1_w = d_in[2];
    const void* fc1_b = d_in[3];
    const void* fc2_w = d_in[4];
    const void* fc2_b = d_in[5];
    const void* d1_w  = d_in[6];
    const void* d1_b  = d_in[7];
    const void* d2_w  = d_in[8];
    const void* d2_b  = d_in[9];
    const void* g1_w  = d_in[10];
    const void* g1_b  = d_in[11];
    const void* g2_w  = d_in[12];
    const void* g2_b  = d_in[13];
    const void* wq_w  = d_in[14];
    const void* wk_w  = d_in[15];
    const void* wv_w  = d_in[16];
    const void* sim_w = d_in[17];
    const void* sim_b = d_in[18];

    detect_kernel<<<1, 64, 0, stream>>>(feat);

    const size_t need_qkv = (size_t)3 * BB * NN * DM * sizeof(float);
    const size_t need_knn = (size_t)BB * NN * KK * sizeof(int);

    if (ws_size >= need_qkv + need_knn && d_ws != nullptr) {
        float* qbuf = (float*)d_ws;
        float* kbuf = qbuf + (size_t)BB * NN * DM;
        float* vbuf = kbuf + (size_t)BB * NN * DM;
        int*   knn  = (int*)(vbuf + (size_t)BB * NN * DM);
        qkv_kernel<<<BB * NN, DM, 0, stream>>>(feat, fc1_w, fc1_b, wq_w, wk_w, wv_w, qbuf, kbuf, vbuf);
        knn_kernel<<<BB * 16, 256, 0, stream>>>(xyz, knn, KK, d_out, 0);
        attn_kernel<false><<<BB * NN, DM, 0, stream>>>(
            xyz, feat, fc1_w, fc1_b, fc2_w, fc2_b, d1_w, d1_b, d2_w, d2_b,
            g1_w, g1_b, g2_w, g2_b, sim_w, sim_b, wq_w, wk_w, wv_w,
            qbuf, kbuf, vbuf, knn, KK, 0, d_out);
    } else if (ws_size >= need_knn && d_ws != nullptr) {
        int* knn = (int*)d_ws;
        knn_kernel<<<BB * 16, 256, 0, stream>>>(xyz, knn, KK, d_out, 0);
        attn_kernel<true><<<BB * NN, DM, 0, stream>>>(
            xyz, feat, fc1_w, fc1_b, fc2_w, fc2_b, d1_w, d1_b, d2_w, d2_b,
            g1_w, g1_b, g2_w, g2_b, sim_w, sim_b, wq_w, wk_w, wv_w,
            nullptr, nullptr, nullptr, knn, KK, 0, d_out);
    } else {
        // zero-workspace: stage knn inside each point's own out1 slice
        // (per-dtype base/stride derived on device from g_flag).
        knn_kernel<<<BB * 16, 256, 0, stream>>>(xyz, nullptr, 0, d_out, 1);
        attn_kernel<true><<<BB * NN, DM, 0, stream>>>(
            xyz, feat, fc1_w, fc1_b, fc2_w, fc2_b, d1_w, d1_b, d2_w, d2_b,
            g1_w, g1_b, g2_w, g2_b, sim_w, sim_b, wq_w, wk_w, wv_w,
            nullptr, nullptr, nullptr, nullptr, 0, 1, d_out);
    }
}

// Round 5
// 1150.076 us; speedup vs baseline: 2.2892x; 2.2892x over previous
//
#include <hip/hip_runtime.h>
#include <hip/hip_bf16.h>

#define BB 4
#define NN 4096
#define KK 16
#define DP 64
#define DM 128
#define DMP 132   // padded LDS row stride (floats); 528 B, 16B-aligned
#define EPSF 1e-8f
#define OUT0N ((size_t)BB * NN * DP)   // elements in out0

typedef unsigned short u16t;

__device__ int g_flag;   // 0 = buffers are fp32, 1 = buffers are bf16

__device__ __forceinline__ float u2f(u16t u) {
    unsigned int x = ((unsigned int)u) << 16;
    return __uint_as_float(x);
}
__device__ __forceinline__ u16t f2u(float v) {
    __hip_bfloat16 h = __float2bfloat16(v);
    return *(u16t*)&h;
}

// ---------------- dtype-abstracted IO -----------------
template<int DT> struct IO;
template<> struct IO<0> {   // fp32
    static __device__ __forceinline__ float ld(const void* p, size_t i) { return ((const float*)p)[i]; }
    static __device__ __forceinline__ void ld4(const void* p, size_t i, float o[4]) {
        float4 v = *(const float4*)((const float*)p + i);
        o[0] = v.x; o[1] = v.y; o[2] = v.z; o[3] = v.w;
    }
    static __device__ __forceinline__ void st(void* p, size_t i, float v) { ((float*)p)[i] = v; }
};
template<> struct IO<1> {   // bf16
    static __device__ __forceinline__ float ld(const void* p, size_t i) { return u2f(((const u16t*)p)[i]); }
    static __device__ __forceinline__ void ld4(const void* p, size_t i, float o[4]) {
        ushort4 v = *(const ushort4*)((const u16t*)p + i);
        o[0] = u2f(v.x); o[1] = u2f(v.y); o[2] = u2f(v.z); o[3] = u2f(v.w);
    }
    static __device__ __forceinline__ void st(void* p, size_t i, float v) { ((u16t*)p)[i] = f2u(v); }
};

// ---------------- dtype detector ----------------------
__global__ __launch_bounds__(64) void detect_kernel(const void* feat) {
    const int tid = threadIdx.x;
    float x = u2f(((const u16t*)feat)[2 * tid]);
    float a = fabsf(x);
    bool sane = (x == 0.0f) || (a > 1e-4f && a < 50.0f);   // NaN/inf -> false
    unsigned long long m = __ballot(sane);
    if (tid == 0) g_flag = (__popcll(m) >= 32) ? 1 : 0;
}

// ---------------- kernel A: qkv ----------------------
struct QkvSmem { float sf[DP]; float sx[DM]; };

template<int DT>
__device__ __forceinline__ void qkv_body(QkvSmem& s,
    const void* feat, const void* fc1_w, const void* fc1_b,
    const void* wq, const void* wk, const void* wv,
    float* __restrict__ qbuf, float* __restrict__ kbuf, float* __restrict__ vbuf)
{
    const int bn = blockIdx.x;
    const int tid = threadIdx.x;
    if (tid < DP) s.sf[tid] = IO<DT>::ld(feat, (size_t)bn * DP + tid);
    __syncthreads();
    float x = IO<DT>::ld(fc1_b, tid);
#pragma unroll 4
    for (int i = 0; i < DP; i++) x = fmaf(s.sf[i], IO<DT>::ld(fc1_w, i * DM + tid), x);
    s.sx[tid] = x;
    __syncthreads();
    float q = 0.f, k = 0.f, v = 0.f;
    for (int i0 = 0; i0 < DM; i0 += 4) {
        float4 xv = *(const float4*)&s.sx[i0];
        const float xs[4] = { xv.x, xv.y, xv.z, xv.w };
#pragma unroll
        for (int j = 0; j < 4; j++) {
            q = fmaf(xs[j], IO<DT>::ld(wq, (i0 + j) * DM + tid), q);
            k = fmaf(xs[j], IO<DT>::ld(wk, (i0 + j) * DM + tid), k);
            v = fmaf(xs[j], IO<DT>::ld(wv, (i0 + j) * DM + tid), v);
        }
    }
    qbuf[(size_t)bn * DM + tid] = q;
    kbuf[(size_t)bn * DM + tid] = k;
    vbuf[(size_t)bn * DM + tid] = v;
}

__global__ __launch_bounds__(128) void qkv_kernel(
    const void* feat, const void* fc1_w, const void* fc1_b,
    const void* wq, const void* wk, const void* wv,
    float* qbuf, float* kbuf, float* vbuf)
{
    __shared__ __align__(16) QkvSmem s;
    if (g_flag) qkv_body<1>(s, feat, fc1_w, fc1_b, wq, wk, wv, qbuf, kbuf, vbuf);
    else        qkv_body<0>(s, feat, fc1_w, fc1_b, wq, wk, wv, qbuf, kbuf, vbuf);
}

// ---------------- kernel B: knn (wave-per-query) -----
// Exact fp32 mirror of: sq_i + sq_j - 2*dot, stable top-K (ties -> low index).
// 8 queries/block (one per wave), 512 threads. Candidates staged once as
// (x,y,z,sq) float4 in 64 KB LDS -> one ds_read_b128 per candidate.
// Per-lane sorted top-16 in registers (unrolled compare-swap bubble, no
// dynamic indexing -> no scratch), then 16-step lexicographic (dist,idx)
// shfl_xor min-merge across the wave == numpy stable argsort order.
template<int DT>
__device__ __forceinline__ void knn_body(float4* __restrict__ sc,
    const void* xyz, int* dst, int dstride, void* dout, int in_out)
{
    if (in_out) {
        if (DT) { dst = (int*)((u16t*)dout + OUT0N); dstride = (KK * DM) / 2; }
        else    { dst = (int*)((float*)dout + OUT0N); dstride = KK * DM; }
    }
    const int b = blockIdx.x >> 9;             // 512 blocks per batch
    const int tid = threadIdx.x;
    for (int j = tid; j < NN; j += 512) {
        float x = IO<DT>::ld(xyz, ((size_t)b * NN + j) * 3 + 0);
        float y = IO<DT>::ld(xyz, ((size_t)b * NN + j) * 3 + 1);
        float z = IO<DT>::ld(xyz, ((size_t)b * NN + j) * 3 + 2);
        float sq = __fadd_rn(__fadd_rn(__fmul_rn(x, x), __fmul_rn(y, y)), __fmul_rn(z, z));
        sc[j] = make_float4(x, y, z, sq);
    }
    __syncthreads();
    const int lane = tid & 63;
    const int wave = tid >> 6;
    const int r = ((blockIdx.x & 511) << 3) + wave;   // query row within batch
    const float4 qc = sc[r];                          // wave-uniform broadcast

    float d[KK];
    int id[KK];
#pragma unroll
    for (int t = 0; t < KK; t++) { d[t] = 3.4e38f; id[t] = 0x7fffffff; }

    for (int j = lane; j < NN; j += 64) {
        const float4 c = sc[j];
        const float dot = __fadd_rn(__fadd_rn(__fmul_rn(qc.x, c.x), __fmul_rn(qc.y, c.y)),
                                    __fmul_rn(qc.z, c.z));
        const float dist = __fsub_rn(__fadd_rn(qc.w, c.w), __fmul_rn(2.0f, dot));
        if (dist < d[KK - 1]) {
            float cd = dist; int ci = j;
#pragma unroll
            for (int t = 0; t < KK; t++) {
                const bool sw = (cd < d[t]);          // strict: stable ties
                const float od = d[t]; const int oi = id[t];
                d[t]  = sw ? cd : d[t];
                id[t] = sw ? ci : id[t];
                cd = sw ? od : cd;
                ci = sw ? oi : ci;
            }
        }
    }

    // wave merge: 16x pop-min over 64 sorted lists
    const size_t base = (size_t)(b * NN + r) * (size_t)dstride;
#pragma unroll
    for (int t = 0; t < KK; t++) {
        float bd = d[0]; int bi = id[0];
#pragma unroll
        for (int off = 32; off >= 1; off >>= 1) {
            const float od = __shfl_xor(bd, off, 64);
            const int   oi = __shfl_xor(bi, off, 64);
            if (od < bd || (od == bd && oi < bi)) { bd = od; bi = oi; }
        }
        const bool win = (d[0] == bd) && (id[0] == bi);   // unique (dist,idx)
        if (win) {
#pragma unroll
            for (int u = 0; u < KK - 1; u++) { d[u] = d[u + 1]; id[u] = id[u + 1]; }
            d[KK - 1] = 3.4e38f; id[KK - 1] = 0x7fffffff;
        }
        if (lane == t) dst[base + t] = bi;
    }
}

__global__ __launch_bounds__(512) void knn_kernel(
    const void* xyz, int* dst, int dstride, void* dout, int in_out)
{
    __shared__ __align__(16) float4 sc[NN];   // 64 KB
    if (g_flag) knn_body<1>(sc, xyz, dst, dstride, dout, in_out);
    else        knn_body<0>(sc, xyz, dst, dstride, dout, in_out);
}

// ---------------- GEMM tile helper -------------------
template<int DT>
__device__ __forceinline__ void gemm_tile(const float* __restrict__ IN,
                                          const void* __restrict__ W, int woff,
                                          int kg, int f0, float acc[4][4])
{
#pragma unroll
    for (int a = 0; a < 4; a++)
#pragma unroll
        for (int c = 0; c < 4; c++) acc[a][c] = 0.f;
    for (int i0 = 0; i0 < DM; i0 += 4) {
        float w[4][4];
#pragma unroll
        for (int j = 0; j < 4; j++) IO<DT>::ld4(W, (size_t)woff + (i0 + j) * DM + f0, w[j]);
#pragma unroll
        for (int kk = 0; kk < 4; kk++) {
            float4 x4 = *(const float4*)(IN + (kg * 4 + kk) * DMP + i0);
            const float xs[4] = { x4.x, x4.y, x4.z, x4.w };
#pragma unroll
            for (int ff = 0; ff < 4; ff++)
#pragma unroll
                for (int j = 0; j < 4; j++)
                    acc[kk][ff] = fmaf(xs[j], w[j][ff], acc[kk][ff]);
        }
    }
}

// ---------------- kernel C: attn ---------------------
template<bool FUSED> struct AttnSmem {
    float Kb[KK * DMP], Vb[KK * DMP], PE[KK * DMP], T0[KK * DMP], T1[KK * DMP];
    float s_q[DM], sres[DM];
    float SF[FUSED ? 17 * DP : 1];
    float X[FUSED ? 17 * DMP : 1];
    float srp[KK][3];
    float ssim[KK], skn[KK], sdot[KK];
    float sqn;
    int sidx[KK];
};

template<int DT, bool FUSED>
__device__ __forceinline__ void attn_body(AttnSmem<FUSED>& s,
    const void* xyz, const void* feat,
    const void* fc1_w, const void* fc1_b, const void* fc2_w, const void* fc2_b,
    const void* d1_w, const void* d1_b, const void* d2_w, const void* d2_b,
    const void* g1_w, const void* g1_b, const void* g2_w, const void* g2_b,
    const void* sim_w, const void* sim_b,
    const void* wq, const void* wk, const void* wv,
    const float* __restrict__ qbuf, const float* __restrict__ kbuf, const float* __restrict__ vbuf,
    const int* knn, int knn_stride, int knn_in_out, void* dout)
{
    void* out0 = dout;
    void* out1 = DT ? (void*)((u16t*)dout + OUT0N) : (void*)((float*)dout + OUT0N);
    if (knn_in_out) {
        if (DT) { knn = (const int*)((const u16t*)dout + OUT0N); knn_stride = (KK * DM) / 2; }
        else    { knn = (const int*)((const float*)dout + OUT0N); knn_stride = KK * DM; }
    }

    const int bn = blockIdx.x;
    const int b = bn >> 12;
    const int tid = threadIdx.x;
    const int f = tid;
    const int f0 = (tid & 31) * 4;
    const int kg = tid >> 5;

    if (tid < KK) {
        int sv = knn[(size_t)bn * knn_stride + tid];
        sv = (sv < 0) ? 0 : (sv > NN - 1 ? NN - 1 : sv);   // defensive, never OOB
        s.sidx[tid] = sv;
    }
    __syncthreads();

    if constexpr (FUSED) {
        for (int idx = tid; idx < 17 * DP; idx += 128) {
            const int r = idx >> 6, c = idx & 63;
            const int row = (r < KK) ? ((b << 12) + s.sidx[r]) : bn;
            s.SF[idx] = IO<DT>::ld(feat, (size_t)row * DP + c);
        }
        __syncthreads();
        float xacc[17];
        const float fb = IO<DT>::ld(fc1_b, tid);
#pragma unroll
        for (int r = 0; r < 17; r++) xacc[r] = fb;
        for (int i = 0; i < DP; i++) {
            const float w = IO<DT>::ld(fc1_w, i * DM + tid);
#pragma unroll
            for (int r = 0; r < 17; r++) xacc[r] = fmaf(s.SF[r * DP + i], w, xacc[r]);
        }
#pragma unroll
        for (int r = 0; r < 17; r++) s.X[r * DMP + tid] = xacc[r];
        __syncthreads();
        {
            float a2[4][4];
            gemm_tile<DT>(s.X, wk, 0, kg, f0, a2);
#pragma unroll
            for (int kk = 0; kk < 4; kk++)
                *(float4*)&s.Kb[(kg * 4 + kk) * DMP + f0] =
                    make_float4(a2[kk][0], a2[kk][1], a2[kk][2], a2[kk][3]);
            gemm_tile<DT>(s.X, wv, 0, kg, f0, a2);
#pragma unroll
            for (int kk = 0; kk < 4; kk++)
                *(float4*)&s.Vb[(kg * 4 + kk) * DMP + f0] =
                    make_float4(a2[kk][0], a2[kk][1], a2[kk][2], a2[kk][3]);
        }
        {
            float qv = 0.f;
            for (int i0 = 0; i0 < DM; i0 += 4) {
                float4 x4 = *(const float4*)&s.X[16 * DMP + i0];
                const float xs[4] = { x4.x, x4.y, x4.z, x4.w };
#pragma unroll
                for (int j = 0; j < 4; j++)
                    qv = fmaf(xs[j], IO<DT>::ld(wq, (i0 + j) * DM + tid), qv);
            }
            s.s_q[tid] = qv;
        }
    } else {
        s.s_q[f] = qbuf[(size_t)bn * DM + f];
#pragma unroll
        for (int k = 0; k < KK; k++) {
            const int row = (b << 12) + s.sidx[k];
            s.Kb[k * DMP + f] = kbuf[(size_t)row * DM + f];
            s.Vb[k * DMP + f] = vbuf[(size_t)row * DM + f];
        }
    }
    if (tid < KK) {
        const int row = (b << 12) + s.sidx[tid];
#pragma unroll
        for (int c = 0; c < 3; c++)
            s.srp[tid][c] = IO<DT>::ld(xyz, (size_t)bn * 3 + c) - IO<DT>::ld(xyz, (size_t)row * 3 + c);
    }
    __syncthreads();

    // norms + q.k dots
    if (tid < KK) {
        float sk = 0.f, sd = 0.f;
        for (int i = 0; i < DM; i++) {
            float v2 = s.Kb[tid * DMP + i];
            sk = fmaf(v2, v2, sk);
            sd = fmaf(s.s_q[i], v2, sd);
        }
        s.skn[tid] = fmaxf(sqrtf(sk), EPSF);
        s.sdot[tid] = sd;
    } else if (tid == KK) {
        float sqq = 0.f;
        for (int i = 0; i < DM; i++) { float v2 = s.s_q[i]; sqq = fmaf(v2, v2, sqq); }
        s.sqn = fmaxf(sqrtf(sqq), EPSF);
    }
    __syncthreads();
    if (tid < KK) s.ssim[tid] = s.sdot[tid] / (s.sqn * s.skn[tid]);
#pragma unroll
    for (int k = 0; k < KK; k++) s.T0[k * DMP + f] = s.s_q[f] - s.Kb[k * DMP + f];
    __syncthreads();

    float acc[4][4];

    // rel_qk = [sim, q-k] @ sim_w + sim_b  -> T1
    gemm_tile<DT>(s.T0, sim_w, DM, kg, f0, acc);
    {
        float w0f[4], sbf[4];
        IO<DT>::ld4(sim_w, f0, w0f);
        IO<DT>::ld4(sim_b, f0, sbf);
#pragma unroll
        for (int kk = 0; kk < 4; kk++) {
            float sm = s.ssim[kg * 4 + kk];
            float4 o;
            o.x = fmaf(sm, w0f[0], acc[kk][0]) + sbf[0];
            o.y = fmaf(sm, w0f[1], acc[kk][1]) + sbf[1];
            o.z = fmaf(sm, w0f[2], acc[kk][2]) + sbf[2];
            o.w = fmaf(sm, w0f[3], acc[kk][3]) + sbf[3];
            *(float4*)&s.T1[(kg * 4 + kk) * DMP + f0] = o;
        }
    }
    __syncthreads();

    // h = relu(rel_pos @ d1_w + d1_b) -> T0
    {
        float w0 = IO<DT>::ld(d1_w, 0 * DM + f), w1 = IO<DT>::ld(d1_w, 1 * DM + f),
              w2 = IO<DT>::ld(d1_w, 2 * DM + f);
        float hb = IO<DT>::ld(d1_b, f);
#pragma unroll
        for (int k = 0; k < KK; k++) {
            float h = fmaf(s.srp[k][2], w2, fmaf(s.srp[k][1], w1, fmaf(s.srp[k][0], w0, hb)));
            s.T0[k * DMP + f] = fmaxf(h, 0.f);
        }
    }
    __syncthreads();

    // pos_enc = h @ d2_w + d2_b -> PE
    gemm_tile<DT>(s.T0, d2_w, 0, kg, f0, acc);
    {
        float bf[4];
        IO<DT>::ld4(d2_b, f0, bf);
#pragma unroll
        for (int kk = 0; kk < 4; kk++)
            *(float4*)&s.PE[(kg * 4 + kk) * DMP + f0] =
                make_float4(acc[kk][0] + bf[0], acc[kk][1] + bf[1],
                            acc[kk][2] + bf[2], acc[kk][3] + bf[3]);
    }
    __syncthreads();

    // T0 = T1 + PE
#pragma unroll
    for (int kk = 0; kk < 4; kk++) {
        const int row = (kg * 4 + kk) * DMP + f0;
        float4 a4 = *(const float4*)&s.T1[row];
        float4 p4 = *(const float4*)&s.PE[row];
        *(float4*)&s.T0[row] = make_float4(a4.x + p4.x, a4.y + p4.y, a4.z + p4.z, a4.w + p4.w);
    }
    __syncthreads();

    // T1 = relu(T0 @ g1_w + g1_b)
    gemm_tile<DT>(s.T0, g1_w, 0, kg, f0, acc);
    {
        float bf[4];
        IO<DT>::ld4(g1_b, f0, bf);
#pragma unroll
        for (int kk = 0; kk < 4; kk++)
            *(float4*)&s.T1[(kg * 4 + kk) * DMP + f0] =
                make_float4(fmaxf(acc[kk][0] + bf[0], 0.f), fmaxf(acc[kk][1] + bf[1], 0.f),
                            fmaxf(acc[kk][2] + bf[2], 0.f), fmaxf(acc[kk][3] + bf[3], 0.f));
    }
    __syncthreads();

    // T0 = T1 @ g2_w + g2_b
    gemm_tile<DT>(s.T1, g2_w, 0, kg, f0, acc);
    {
        float bf[4];
        IO<DT>::ld4(g2_b, f0, bf);
#pragma unroll
        for (int kk = 0; kk < 4; kk++)
            *(float4*)&s.T0[(kg * 4 + kk) * DMP + f0] =
                make_float4(acc[kk][0] + bf[0], acc[kk][1] + bf[1],
                            acc[kk][2] + bf[2], acc[kk][3] + bf[3]);
    }
    __syncthreads();

    // softmax over K + einsum
    {
        const float sq128 = 11.31370849898476f;
        float tv[KK];
        float m = -3.4e38f;
#pragma unroll
        for (int k = 0; k < KK; k++) { tv[k] = s.T0[k * DMP + f] / sq128; m = fmaxf(m, tv[k]); }
        float ssum = 0.f;
#pragma unroll
        for (int k = 0; k < KK; k++) { tv[k] = expf(tv[k] - m); ssum += tv[k]; }
        float rf = 0.f;
#pragma unroll
        for (int k = 0; k < KK; k++) {
            float a = tv[k] / ssum;
            IO<DT>::st(out1, ((size_t)bn * KK + k) * DM + f, a);
            rf = fmaf(a, s.Vb[k * DMP + f] + s.PE[k * DMP + f], rf);
        }
        s.sres[f] = rf;
    }
    __syncthreads();

    // out0 = res @ fc2_w + fc2_b + features
    if (tid < DP) {
        float o = 0.f;
        for (int i = 0; i < DM; i++) o = fmaf(s.sres[i], IO<DT>::ld(fc2_w, i * DP + tid), o);
        o = o + IO<DT>::ld(fc2_b, tid) + IO<DT>::ld(feat, (size_t)bn * DP + tid);
        IO<DT>::st(out0, (size_t)bn * DP + tid, o);
    }
}

template<bool FUSED>
__global__ __launch_bounds__(128) void attn_kernel(
    const void* xyz, const void* feat,
    const void* fc1_w, const void* fc1_b, const void* fc2_w, const void* fc2_b,
    const void* d1_w, const void* d1_b, const void* d2_w, const void* d2_b,
    const void* g1_w, const void* g1_b, const void* g2_w, const void* g2_b,
    const void* sim_w, const void* sim_b,
    const void* wq, const void* wk, const void* wv,
    const float* qbuf, const float* kbuf, const float* vbuf,
    const int* knn, int knn_stride, int knn_in_out, void* dout)
{
    __shared__ __align__(16) AttnSmem<FUSED> s;
    if (g_flag)
        attn_body<1, FUSED>(s, xyz, feat, fc1_w, fc1_b, fc2_w, fc2_b, d1_w, d1_b, d2_w, d2_b,
                            g1_w, g1_b, g2_w, g2_b, sim_w, sim_b, wq, wk, wv,
                            qbuf, kbuf, vbuf, knn, knn_stride, knn_in_out, dout);
    else
        attn_body<0, FUSED>(s, xyz, feat, fc1_w, fc1_b, fc2_w, fc2_b, d1_w, d1_b, d2_w, d2_b,
                            g1_w, g1_b, g2_w, g2_b, sim_w, sim_b, wq, wk, wv,
                            qbuf, kbuf, vbuf, knn, knn_stride, knn_in_out, dout);
}

// ---------------------------------------------------------------- launch
extern "C" void kernel_launch(void* const* d_in, const int* in_sizes, int n_in,
                              void* d_out, int out_size, void* d_ws, size_t ws_size,
                              hipStream_t stream)
{
    const void* xyz   = d_in[0];
    const void* feat  = d_in[1];
    const void* fc1_w = d_in[2];
    const void* fc1_b = d_in[3];
    const void* fc2_w = d_in[4];
    const void* fc2_b = d_in[5];
    const void* d1_w  = d_in[6];
    const void* d1_b  = d_in[7];
    const void* d2_w  = d_in[8];
    const void* d2_b  = d_in[9];
    const void* g1_w  = d_in[10];
    const void* g1_b  = d_in[11];
    const void* g2_w  = d_in[12];
    const void* g2_b  = d_in[13];
    const void* wq_w  = d_in[14];
    const void* wk_w  = d_in[15];
    const void* wv_w  = d_in[16];
    const void* sim_w = d_in[17];
    const void* sim_b = d_in[18];

    detect_kernel<<<1, 64, 0, stream>>>(feat);

    const size_t need_qkv = (size_t)3 * BB * NN * DM * sizeof(float);
    const size_t need_knn = (size_t)BB * NN * KK * sizeof(int);

    if (ws_size >= need_qkv + need_knn && d_ws != nullptr) {
        float* qbuf = (float*)d_ws;
        float* kbuf = qbuf + (size_t)BB * NN * DM;
        float* vbuf = kbuf + (size_t)BB * NN * DM;
        int*   knn  = (int*)(vbuf + (size_t)BB * NN * DM);
        qkv_kernel<<<BB * NN, DM, 0, stream>>>(feat, fc1_w, fc1_b, wq_w, wk_w, wv_w, qbuf, kbuf, vbuf);
        knn_kernel<<<BB * 512, 512, 0, stream>>>(xyz, knn, KK, d_out, 0);
        attn_kernel<false><<<BB * NN, DM, 0, stream>>>(
            xyz, feat, fc1_w, fc1_b, fc2_w, fc2_b, d1_w, d1_b, d2_w, d2_b,
            g1_w, g1_b, g2_w, g2_b, sim_w, sim_b, wq_w, wk_w, wv_w,
            qbuf, kbuf, vbuf, knn, KK, 0, d_out);
    } else if (ws_size >= need_knn && d_ws != nullptr) {
        int* knn = (int*)d_ws;
        knn_kernel<<<BB * 512, 512, 0, stream>>>(xyz, knn, KK, d_out, 0);
        attn_kernel<true><<<BB * NN, DM, 0, stream>>>(
            xyz, feat, fc1_w, fc1_b, fc2_w, fc2_b, d1_w, d1_b, d2_w, d2_b,
            g1_w, g1_b, g2_w, g2_b, sim_w, sim_b, wq_w, wk_w, wv_w,
            nullptr, nullptr, nullptr, knn, KK, 0, d_out);
    } else {
        knn_kernel<<<BB * 512, 512, 0, stream>>>(xyz, nullptr, 0, d_out, 1);
        attn_kernel<true><<<BB * NN, DM, 0, stream>>>(
            xyz, feat, fc1_w, fc1_b, fc2_w, fc2_b, d1_w, d1_b, d2_w, d2_b,
            g1_w, g1_b, g2_w, g2_b, sim_w, sim_b, wq_w, wk_w, wv_w,
            nullptr, nullptr, nullptr, nullptr, 0, 1, d_out);
    }
}